// Round 1
// baseline (152.623 us; speedup 1.0000x reference)
//
#include <hip/hip_runtime.h>

#define BATCH   8192
#define SDIM    64
#define HDIM    128
#define NB      8
#define UNFOLDS 4

__global__ __launch_bounds__(128) void ltc_kernel(
    const float* __restrict__ input,    // [B,S]
    const float* __restrict__ hidden,   // [B,H]
    const float* __restrict__ s_mu,     // [S,H]
    const float* __restrict__ s_sig,    // [S,H]
    const float* __restrict__ s_W,      // [S,H]
    const float* __restrict__ h_mu,     // [H,H]
    const float* __restrict__ h_sig,    // [H,H]
    const float* __restrict__ h_W,      // [H,H]
    const float* __restrict__ w_tau,    // [H]
    const float* __restrict__ w_A,      // [H]
    const float* __restrict__ elapsed,  // [1]
    float* __restrict__ out)            // [B,H]
{
    const int h  = threadIdx.x;          // 0..127, output feature
    const int b0 = blockIdx.x * NB;      // batch tile base

    __shared__ float st [NB][HDIM];      // current state for NB rows
    __shared__ float xin[NB][SDIM];      // input rows

    const float LOG2E = 1.4426950408889634f;

    // stage NB input rows (NB*SDIM = 512 floats, 128 threads -> 4 each)
    #pragma unroll
    for (int i = 0; i < (NB * SDIM) / HDIM; ++i) {
        int idx = i * HDIM + h;
        int nb  = idx >> 6;      // / SDIM
        int s   = idx & (SDIM - 1);
        xin[nb][s] = input[(b0 + nb) * SDIM + s];
    }
    // stage initial hidden state
    #pragma unroll
    for (int nb = 0; nb < NB; ++nb)
        st[nb][h] = hidden[(b0 + nb) * HDIM + h];
    __syncthreads();

    const float dt = elapsed[0] * (1.0f / UNFOLDS);

    // ---- sensory activation: sens[nb] = sum_s W[s][h] * sigmoid(sig*(x-mu)) ----
    float sens[NB];
    #pragma unroll
    for (int nb = 0; nb < NB; ++nb) sens[nb] = 0.0f;

    for (int s = 0; s < SDIM; ++s) {
        float mu = s_mu [s * HDIM + h];
        float sg = s_sig[s * HDIM + h];
        float w  = s_W  [s * HDIM + h];
        float a  = -LOG2E * sg;      // exp2 arg = a*x + c  ==  -log2e*sg*(x-mu)
        float c  = -a * mu;
        #pragma unroll
        for (int nb = 0; nb < NB; ++nb) {
            float x = xin[nb][s];                               // LDS broadcast
            float e = __builtin_amdgcn_exp2f(fmaf(x, a, c));    // exp(-z)
            float r = __builtin_amdgcn_rcpf(1.0f + e);          // sigmoid(z)
            sens[nb] = fmaf(w, r, sens[nb]);
        }
    }

    const float wT  = w_tau[h];
    const float wA  = w_A[h];
    const float dA  = dt * wA;
    const float dT1 = fmaf(dt, wT, 1.0f) + 1e-8f;   // 1 + dt*w_tau + EPS

    // ---- ODE unfolds ----
    for (int it = 0; it < UNFOLDS; ++it) {
        float acc[NB];
        #pragma unroll
        for (int nb = 0; nb < NB; ++nb) acc[nb] = sens[nb];

        for (int p = 0; p < HDIM; ++p) {
            float mu = h_mu [p * HDIM + h];
            float sg = h_sig[p * HDIM + h];
            float w  = h_W  [p * HDIM + h];
            float a  = -LOG2E * sg;
            float c  = -a * mu;
            #pragma unroll
            for (int nb = 0; nb < NB; ++nb) {
                float x = st[nb][p];                             // LDS broadcast
                float e = __builtin_amdgcn_exp2f(fmaf(x, a, c));
                float r = __builtin_amdgcn_rcpf(1.0f + e);
                acc[nb] = fmaf(w, r, acc[nb]);
            }
        }

        float ns[NB];
        #pragma unroll
        for (int nb = 0; nb < NB; ++nb) {
            float stx  = st[nb][h];
            float resp = acc[nb];
            float num  = fmaf(dA, resp, stx);
            float den  = fmaf(dt, resp, dT1);       // 1 + dt*w_tau + dt*resp + eps
            ns[nb] = num * __builtin_amdgcn_rcpf(den);
        }
        __syncthreads();                 // all reads of st done before overwrite
        #pragma unroll
        for (int nb = 0; nb < NB; ++nb) st[nb][h] = ns[nb];
        __syncthreads();                 // writes visible before next unfold
    }

    // ---- output ----
    #pragma unroll
    for (int nb = 0; nb < NB; ++nb)
        out[(b0 + nb) * HDIM + h] = st[nb][h];
}

extern "C" void kernel_launch(void* const* d_in, const int* in_sizes, int n_in,
                              void* d_out, int out_size, void* d_ws, size_t ws_size,
                              hipStream_t stream) {
    const float* input   = (const float*)d_in[0];
    const float* hidden  = (const float*)d_in[1];
    const float* s_mu    = (const float*)d_in[2];
    const float* s_sig   = (const float*)d_in[3];
    const float* s_W     = (const float*)d_in[4];
    const float* h_mu    = (const float*)d_in[5];
    const float* h_sig   = (const float*)d_in[6];
    const float* h_W     = (const float*)d_in[7];
    const float* w_tau   = (const float*)d_in[8];
    const float* w_A     = (const float*)d_in[9];
    const float* elapsed = (const float*)d_in[10];
    float* out = (float*)d_out;

    dim3 grid(BATCH / NB);
    dim3 block(HDIM);
    ltc_kernel<<<grid, block, 0, stream>>>(input, hidden,
                                           s_mu, s_sig, s_W,
                                           h_mu, h_sig, h_W,
                                           w_tau, w_A, elapsed, out);
}

// Round 2
// 134.923 us; speedup vs baseline: 1.1312x; 1.1312x over previous
//
#include <hip/hip_runtime.h>

#define BATCH   8192
#define SDIM    64
#define HDIM    128
#define NB      4
#define UNFOLDS 4

typedef float f32x2 __attribute__((ext_vector_type(2)));

__device__ __forceinline__ f32x2 sigmoid2(f32x2 z) {
    // sigmoid(z) computed as 1/(1+exp2(z*(-log2e))) with z pre-scaled by caller
    f32x2 e;
    e.x = __builtin_amdgcn_exp2f(z.x);
    e.y = __builtin_amdgcn_exp2f(z.y);
    f32x2 d = e + (f32x2){1.0f, 1.0f};          // v_pk_add_f32
    f32x2 r;
    r.x = __builtin_amdgcn_rcpf(d.x);
    r.y = __builtin_amdgcn_rcpf(d.y);
    return r;
}

__global__ __launch_bounds__(128) void ltc_kernel(
    const float* __restrict__ input,    // [B,S]
    const float* __restrict__ hidden,   // [B,H]
    const float* __restrict__ s_mu,     // [S,H]
    const float* __restrict__ s_sig,    // [S,H]
    const float* __restrict__ s_W,      // [S,H]
    const float* __restrict__ h_mu,     // [H,H]
    const float* __restrict__ h_sig,    // [H,H]
    const float* __restrict__ h_W,      // [H,H]
    const float* __restrict__ w_tau,    // [H]
    const float* __restrict__ w_A,      // [H]
    const float* __restrict__ elapsed,  // [1]
    float* __restrict__ out)            // [B,H]
{
    const int h  = threadIdx.x;          // 0..127, output feature
    const int b0 = blockIdx.x * NB;      // batch tile base

    __shared__ float st [NB][HDIM];      // current state for NB rows
    __shared__ float xin[NB][SDIM];      // input rows

    const float LOG2E = 1.4426950408889634f;

    // stage NB input rows (NB*SDIM = 256 floats, 128 threads -> 2 each)
    #pragma unroll
    for (int i = 0; i < (NB * SDIM) / HDIM; ++i) {
        int idx = i * HDIM + h;
        int nb  = idx >> 6;      // / SDIM
        int s   = idx & (SDIM - 1);
        xin[nb][s] = input[(b0 + nb) * SDIM + s];
    }
    // stage initial hidden state
    #pragma unroll
    for (int nb = 0; nb < NB; ++nb)
        st[nb][h] = hidden[(b0 + nb) * HDIM + h];
    __syncthreads();

    const float dt = elapsed[0] * (1.0f / UNFOLDS);

    // ---- sensory activation: sens[nb] = sum_s W[s][h] * sigmoid(sig*(x-mu)) ----
    f32x2 sens0 = {0.0f, 0.0f};
    f32x2 sens1 = {0.0f, 0.0f};

    for (int s = 0; s < SDIM; ++s) {
        float mu = s_mu [s * HDIM + h];
        float sg = s_sig[s * HDIM + h];
        float w  = s_W  [s * HDIM + h];
        float a  = -LOG2E * sg;      // exp2 arg = a*x + c == -log2e*sg*(x-mu)
        float c  = -a * mu;
        f32x2 av = {a, a}, cv = {c, c}, wv = {w, w};
        f32x2 x0 = {xin[0][s], xin[1][s]};            // LDS broadcast
        f32x2 x1 = {xin[2][s], xin[3][s]};
        f32x2 r0 = sigmoid2(__builtin_elementwise_fma(x0, av, cv));
        f32x2 r1 = sigmoid2(__builtin_elementwise_fma(x1, av, cv));
        sens0 = __builtin_elementwise_fma(wv, r0, sens0);
        sens1 = __builtin_elementwise_fma(wv, r1, sens1);
    }

    const float wT  = w_tau[h];
    const float wA  = w_A[h];
    const float dA  = dt * wA;
    const float dT1 = fmaf(dt, wT, 1.0f) + 1e-8f;   // 1 + dt*w_tau + EPS
    const f32x2 dAv  = {dA, dA};
    const f32x2 dtv  = {dt, dt};
    const f32x2 dT1v = {dT1, dT1};

    // ---- ODE unfolds ----
    for (int it = 0; it < UNFOLDS; ++it) {
        f32x2 acc0 = sens0;
        f32x2 acc1 = sens1;

        for (int p = 0; p < HDIM; ++p) {
            float mu = h_mu [p * HDIM + h];
            float sg = h_sig[p * HDIM + h];
            float w  = h_W  [p * HDIM + h];
            float a  = -LOG2E * sg;
            float c  = -a * mu;
            f32x2 av = {a, a}, cv = {c, c}, wv = {w, w};
            f32x2 x0 = {st[0][p], st[1][p]};          // LDS broadcast
            f32x2 x1 = {st[2][p], st[3][p]};
            f32x2 r0 = sigmoid2(__builtin_elementwise_fma(x0, av, cv));
            f32x2 r1 = sigmoid2(__builtin_elementwise_fma(x1, av, cv));
            acc0 = __builtin_elementwise_fma(wv, r0, acc0);
            acc1 = __builtin_elementwise_fma(wv, r1, acc1);
        }

        // new state = (st + dA*resp) / (1 + dt*w_tau + dt*resp + eps)
        f32x2 sx0 = {st[0][h], st[1][h]};
        f32x2 sx1 = {st[2][h], st[3][h]};
        f32x2 num0 = __builtin_elementwise_fma(dAv, acc0, sx0);
        f32x2 num1 = __builtin_elementwise_fma(dAv, acc1, sx1);
        f32x2 den0 = __builtin_elementwise_fma(dtv, acc0, dT1v);
        f32x2 den1 = __builtin_elementwise_fma(dtv, acc1, dT1v);
        f32x2 ns0, ns1;
        ns0.x = num0.x * __builtin_amdgcn_rcpf(den0.x);
        ns0.y = num0.y * __builtin_amdgcn_rcpf(den0.y);
        ns1.x = num1.x * __builtin_amdgcn_rcpf(den1.x);
        ns1.y = num1.y * __builtin_amdgcn_rcpf(den1.y);

        __syncthreads();                 // all reads of st done before overwrite
        st[0][h] = ns0.x;
        st[1][h] = ns0.y;
        st[2][h] = ns1.x;
        st[3][h] = ns1.y;
        __syncthreads();                 // writes visible before next unfold
    }

    // ---- output ----
    #pragma unroll
    for (int nb = 0; nb < NB; ++nb)
        out[(b0 + nb) * HDIM + h] = st[nb][h];
}

extern "C" void kernel_launch(void* const* d_in, const int* in_sizes, int n_in,
                              void* d_out, int out_size, void* d_ws, size_t ws_size,
                              hipStream_t stream) {
    const float* input   = (const float*)d_in[0];
    const float* hidden  = (const float*)d_in[1];
    const float* s_mu    = (const float*)d_in[2];
    const float* s_sig   = (const float*)d_in[3];
    const float* s_W     = (const float*)d_in[4];
    const float* h_mu    = (const float*)d_in[5];
    const float* h_sig   = (const float*)d_in[6];
    const float* h_W     = (const float*)d_in[7];
    const float* w_tau   = (const float*)d_in[8];
    const float* w_A     = (const float*)d_in[9];
    const float* elapsed = (const float*)d_in[10];
    float* out = (float*)d_out;

    dim3 grid(BATCH / NB);
    dim3 block(HDIM);
    ltc_kernel<<<grid, block, 0, stream>>>(input, hidden,
                                           s_mu, s_sig, s_W,
                                           h_mu, h_sig, h_W,
                                           w_tau, w_A, elapsed, out);
}